// Round 1
// baseline (356.246 us; speedup 1.0000x reference)
//
#include <hip/hip_runtime.h>
#include <math.h>

#define Bb 256
#define Nn 256
#define Dd 512
#define Cc 1024

__device__ __forceinline__ float waveReduceSum(float v) {
    #pragma unroll
    for (int off = 32; off > 0; off >>= 1)
        v += __shfl_xor(v, off, 64);
    return v;
}
__device__ __forceinline__ float waveReduceMax(float v) {
    #pragma unroll
    for (int off = 32; off > 0; off >>= 1)
        v = fmaxf(v, __shfl_xor(v, off, 64));
    return v;
}

// A: normalize text rows. grid = Cc blocks, 64 threads (1 wave). Each lane: 8 floats.
__global__ void k_txtnorm(const float* __restrict__ txt, float* __restrict__ txt_n) {
    const int c = blockIdx.x;
    const int lane = threadIdx.x;  // 0..63
    const float* row = txt + (size_t)c * Dd + lane * 8;
    float4 a = *(const float4*)row;
    float4 b = *(const float4*)(row + 4);
    float ss = a.x*a.x + a.y*a.y + a.z*a.z + a.w*a.w
             + b.x*b.x + b.y*b.y + b.z*b.z + b.w*b.w;
    ss = waveReduceSum(ss);
    const float inv = 1.0f / fmaxf(sqrtf(ss), 1e-12f);
    float* out = txt_n + (size_t)c * Dd + lane * 8;
    a.x *= inv; a.y *= inv; a.z *= inv; a.w *= inv;
    b.x *= inv; b.y *= inv; b.z *= inv; b.w *= inv;
    *(float4*)out = a;
    *(float4*)(out + 4) = b;
}

// B: per-token dot with txt_n[gt[b]] and sumsq. One wave per (b,n) row.
// grid = B*N/4 blocks of 256 threads (4 waves).
__global__ void k_simgt(const float* __restrict__ toks, const float* __restrict__ txt_n,
                        const int* __restrict__ pid,
                        float* __restrict__ simsgt, float* __restrict__ invn) {
    const int wv = threadIdx.x >> 6;
    const int lane = threadIdx.x & 63;
    const int row = blockIdx.x * 4 + wv;          // 0..B*N-1
    const int b = row >> 8;                        // N = 256
    const int g = pid[b];
    const float* t = toks + (size_t)row * Dd + lane * 8;
    const float* x = txt_n + (size_t)g * Dd + lane * 8;
    float4 t0 = *(const float4*)t;
    float4 t1 = *(const float4*)(t + 4);
    float4 x0 = *(const float4*)x;
    float4 x1 = *(const float4*)(x + 4);
    float dot = t0.x*x0.x + t0.y*x0.y + t0.z*x0.z + t0.w*x0.w
              + t1.x*x1.x + t1.y*x1.y + t1.z*x1.z + t1.w*x1.w;
    float ss  = t0.x*t0.x + t0.y*t0.y + t0.z*t0.z + t0.w*t0.w
              + t1.x*t1.x + t1.y*t1.y + t1.z*t1.z + t1.w*t1.w;
    dot = waveReduceSum(dot);
    ss = waveReduceSum(ss);
    if (lane == 0) {
        const float inv = 1.0f / fmaxf(sqrtf(ss), 1e-12f);
        simsgt[row] = dot * inv;
        invn[row] = inv;
    }
}

// C: per-b softmax over n; coef = w * inv_norm. grid = B blocks, 256 threads.
__global__ void k_softmax(const float* __restrict__ simsgt, const float* __restrict__ invn,
                          const float* __restrict__ log_attn_tau, float* __restrict__ coef) {
    const int b = blockIdx.x;
    const int t = threadIdx.x;
    float at = expf(log_attn_tau[0]);
    at = fminf(fmaxf(at, 0.01f), 1.0f);
    const float s = simsgt[b * Nn + t];
    __shared__ float redm[4], reds[4];
    float m = waveReduceMax(s);
    if ((t & 63) == 0) redm[t >> 6] = m;
    __syncthreads();
    m = fmaxf(fmaxf(redm[0], redm[1]), fmaxf(redm[2], redm[3]));
    const float e = expf((s - m) / at);
    float sum = waveReduceSum(e);
    if ((t & 63) == 0) reds[t >> 6] = sum;
    __syncthreads();
    sum = reds[0] + reds[1] + reds[2] + reds[3];
    coef[b * Nn + t] = (e / sum) * invn[b * Nn + t];
}

// D: partial q. grid = (B, 4), 128 threads; block handles 64 n's, one float4 column/thread.
__global__ void k_qpart(const float* __restrict__ toks, const float* __restrict__ coef,
                        float* __restrict__ qpart) {
    const int b = blockIdx.x;
    const int seg = blockIdx.y;
    const int t = threadIdx.x;  // 0..127
    __shared__ float cf[64];
    if (t < 64) cf[t] = coef[b * Nn + seg * 64 + t];
    __syncthreads();
    const float4* tp = (const float4*)(toks + ((size_t)(b * Nn + seg * 64)) * Dd) + t;
    float4 acc = make_float4(0.f, 0.f, 0.f, 0.f);
    #pragma unroll 4
    for (int n = 0; n < 64; ++n) {
        const float w = cf[n];
        float4 v = tp[(size_t)n * (Dd / 4)];
        acc.x = fmaf(w, v.x, acc.x);
        acc.y = fmaf(w, v.y, acc.y);
        acc.z = fmaf(w, v.z, acc.z);
        acc.w = fmaf(w, v.w, acc.w);
    }
    ((float4*)(qpart + ((size_t)seg * Bb + b) * Dd))[t] = acc;
}

// E: logits = (q . txt_n[c]) / tau, online LSE over c, nll[b]. grid = B blocks, 256 threads.
__global__ void k_nll(const float* __restrict__ qpart, const float* __restrict__ txt_n,
                      const int* __restrict__ pid, const float* __restrict__ log_tau,
                      float* __restrict__ nll) {
    const int b = blockIdx.x;
    const int wv = threadIdx.x >> 6;
    const int lane = threadIdx.x & 63;
    __shared__ float qs[Dd];
    for (int i = threadIdx.x; i < Dd; i += 256) {
        qs[i] = qpart[((size_t)0 * Bb + b) * Dd + i] + qpart[((size_t)1 * Bb + b) * Dd + i]
              + qpart[((size_t)2 * Bb + b) * Dd + i] + qpart[((size_t)3 * Bb + b) * Dd + i];
    }
    __syncthreads();
    float tau = expf(log_tau[0]);
    tau = fminf(fmaxf(tau, 0.01f), 1.0f);
    const float itau = 1.0f / tau;
    const int g = pid[b];
    float qa[8];
    #pragma unroll
    for (int j = 0; j < 8; ++j) qa[j] = qs[lane * 8 + j];
    float m = -INFINITY, s = 0.0f, gl = -INFINITY;
    for (int c = wv; c < Cc; c += 4) {
        const float* x = txt_n + (size_t)c * Dd + lane * 8;
        float4 x0 = *(const float4*)x;
        float4 x1 = *(const float4*)(x + 4);
        float d = qa[0]*x0.x + qa[1]*x0.y + qa[2]*x0.z + qa[3]*x0.w
                + qa[4]*x1.x + qa[5]*x1.y + qa[6]*x1.z + qa[7]*x1.w;
        d = waveReduceSum(d);   // all lanes get full dot (butterfly)
        const float l = d * itau;
        if (c == g) gl = l;
        if (l > m) { s = s * expf(m - l) + 1.0f; m = l; }
        else       { s += expf(l - m); }
    }
    __shared__ float sm[4], ssum[4], sgl[4];
    if (lane == 0) { sm[wv] = m; ssum[wv] = s; sgl[wv] = gl; }
    __syncthreads();
    if (threadIdx.x == 0) {
        const float M = fmaxf(fmaxf(sm[0], sm[1]), fmaxf(sm[2], sm[3]));
        const float S = ssum[0]*expf(sm[0]-M) + ssum[1]*expf(sm[1]-M)
                      + ssum[2]*expf(sm[2]-M) + ssum[3]*expf(sm[3]-M);
        const float lse = M + logf(S);
        const float G = fmaxf(fmaxf(sgl[0], sgl[1]), fmaxf(sgl[2], sgl[3]));
        nll[b] = lse - G;
    }
}

// F: mean over B. 1 block, 256 threads.
__global__ void k_mean(const float* __restrict__ nll, float* __restrict__ out) {
    float v = nll[threadIdx.x];
    __shared__ float red[4];
    v = waveReduceSum(v);
    if ((threadIdx.x & 63) == 0) red[threadIdx.x >> 6] = v;
    __syncthreads();
    if (threadIdx.x == 0) out[0] = (red[0] + red[1] + red[2] + red[3]) * (1.0f / (float)Bb);
}

extern "C" void kernel_launch(void* const* d_in, const int* in_sizes, int n_in,
                              void* d_out, int out_size, void* d_ws, size_t ws_size,
                              hipStream_t stream) {
    const float* toks = (const float*)d_in[0];     // [B,N,D] fp32
    const float* txt = (const float*)d_in[1];      // [C,D] fp32
    const float* log_tau = (const float*)d_in[2];
    const float* log_attn_tau = (const float*)d_in[3];
    const int* pid = (const int*)d_in[4];          // [B] int32
    float* out = (float*)d_out;

    float* ws = (float*)d_ws;
    float* txt_n  = ws;                       // C*D = 524288
    float* coef   = txt_n + (size_t)Cc * Dd;  // B*N = 65536
    float* simsgt = coef + Bb * Nn;           // B*N
    float* invn   = simsgt + Bb * Nn;         // B*N
    float* qpart  = invn + Bb * Nn;           // 4*B*D = 524288
    float* nll    = qpart + (size_t)4 * Bb * Dd;  // B

    k_txtnorm<<<Cc, 64, 0, stream>>>(txt, txt_n);
    k_simgt<<<(Bb * Nn) / 4, 256, 0, stream>>>(toks, txt_n, pid, simsgt, invn);
    k_softmax<<<Bb, 256, 0, stream>>>(simsgt, invn, log_attn_tau, coef);
    k_qpart<<<dim3(Bb, 4), 128, 0, stream>>>(toks, coef, qpart);
    k_nll<<<Bb, 256, 0, stream>>>(qpart, txt_n, pid, log_tau, nll);
    k_mean<<<1, 256, 0, stream>>>(nll, out);
}

// Round 2
// 287.471 us; speedup vs baseline: 1.2392x; 1.2392x over previous
//
#include <hip/hip_runtime.h>
#include <math.h>

#define Bb 256
#define Nn 256
#define Dd 512
#define Cc 1024

__device__ __forceinline__ float waveReduceSum(float v) {
    #pragma unroll
    for (int off = 32; off > 0; off >>= 1)
        v += __shfl_xor(v, off, 64);
    return v;
}
__device__ __forceinline__ float waveReduceMax(float v) {
    #pragma unroll
    for (int off = 32; off > 0; off >>= 1)
        v = fmaxf(v, __shfl_xor(v, off, 64));
    return v;
}

// A: normalize text rows. grid = Cc blocks, 64 threads (1 wave). Each lane: 8 floats.
__global__ void k_txtnorm(const float* __restrict__ txt, float* __restrict__ txt_n) {
    const int c = blockIdx.x;
    const int lane = threadIdx.x;  // 0..63
    const float* row = txt + (size_t)c * Dd + lane * 8;
    float4 a = *(const float4*)row;
    float4 b = *(const float4*)(row + 4);
    float ss = a.x*a.x + a.y*a.y + a.z*a.z + a.w*a.w
             + b.x*b.x + b.y*b.y + b.z*b.z + b.w*b.w;
    ss = waveReduceSum(ss);
    const float inv = 1.0f / fmaxf(sqrtf(ss), 1e-12f);
    float* out = txt_n + (size_t)c * Dd + lane * 8;
    a.x *= inv; a.y *= inv; a.z *= inv; a.w *= inv;
    b.x *= inv; b.y *= inv; b.z *= inv; b.w *= inv;
    *(float4*)out = a;
    *(float4*)(out + 4) = b;
}

// A2: transpose txt_n [C,D] -> txt_t [D,C]. 32x32 LDS tiles (+1 pad).
// grid = (C/32, D/32), 256 threads.
__global__ void k_transpose(const float* __restrict__ txt_n, float* __restrict__ txt_t) {
    __shared__ float tile[32][33];
    const int c0 = blockIdx.x * 32;
    const int d0 = blockIdx.y * 32;
    const int tx = threadIdx.x & 31;
    const int ty = threadIdx.x >> 5;   // 0..7
    #pragma unroll
    for (int r = ty; r < 32; r += 8)
        tile[r][tx] = txt_n[(size_t)(c0 + r) * Dd + d0 + tx];
    __syncthreads();
    #pragma unroll
    for (int r = ty; r < 32; r += 8)
        txt_t[(size_t)(d0 + r) * Cc + c0 + tx] = tile[tx][r];
}

// B: per-token dot with txt_n[gt[b]] and sumsq. One wave per (b,n) row.
__global__ void k_simgt(const float* __restrict__ toks, const float* __restrict__ txt_n,
                        const int* __restrict__ pid,
                        float* __restrict__ simsgt, float* __restrict__ invn) {
    const int wv = threadIdx.x >> 6;
    const int lane = threadIdx.x & 63;
    const int row = blockIdx.x * 4 + wv;          // 0..B*N-1
    const int b = row >> 8;                        // N = 256
    const int g = pid[b];
    const float* t = toks + (size_t)row * Dd + lane * 8;
    const float* x = txt_n + (size_t)g * Dd + lane * 8;
    float4 t0 = *(const float4*)t;
    float4 t1 = *(const float4*)(t + 4);
    float4 x0 = *(const float4*)x;
    float4 x1 = *(const float4*)(x + 4);
    float dot = t0.x*x0.x + t0.y*x0.y + t0.z*x0.z + t0.w*x0.w
              + t1.x*x1.x + t1.y*x1.y + t1.z*x1.z + t1.w*x1.w;
    float ss  = t0.x*t0.x + t0.y*t0.y + t0.z*t0.z + t0.w*t0.w
              + t1.x*t1.x + t1.y*t1.y + t1.z*t1.z + t1.w*t1.w;
    dot = waveReduceSum(dot);
    ss = waveReduceSum(ss);
    if (lane == 0) {
        const float inv = 1.0f / fmaxf(sqrtf(ss), 1e-12f);
        simsgt[row] = dot * inv;
        invn[row] = inv;
    }
}

// C: per-b softmax over n; coef = w * inv_norm. grid = B blocks, 256 threads.
__global__ void k_softmax(const float* __restrict__ simsgt, const float* __restrict__ invn,
                          const float* __restrict__ log_attn_tau, float* __restrict__ coef) {
    const int b = blockIdx.x;
    const int t = threadIdx.x;
    float at = expf(log_attn_tau[0]);
    at = fminf(fmaxf(at, 0.01f), 1.0f);
    const float s = simsgt[b * Nn + t];
    __shared__ float redm[4], reds[4];
    float m = waveReduceMax(s);
    if ((t & 63) == 0) redm[t >> 6] = m;
    __syncthreads();
    m = fmaxf(fmaxf(redm[0], redm[1]), fmaxf(redm[2], redm[3]));
    const float e = expf((s - m) / at);
    float sum = waveReduceSum(e);
    if ((t & 63) == 0) reds[t >> 6] = sum;
    __syncthreads();
    sum = reds[0] + reds[1] + reds[2] + reds[3];
    coef[b * Nn + t] = (e / sum) * invn[b * Nn + t];
}

// D: partial q. grid = (B, 4), 128 threads; block handles 64 n's, one float4 column/thread.
__global__ void k_qpart(const float* __restrict__ toks, const float* __restrict__ coef,
                        float* __restrict__ qpart) {
    const int b = blockIdx.x;
    const int seg = blockIdx.y;
    const int t = threadIdx.x;  // 0..127
    __shared__ float cf[64];
    if (t < 64) cf[t] = coef[b * Nn + seg * 64 + t];
    __syncthreads();
    const float4* tp = (const float4*)(toks + ((size_t)(b * Nn + seg * 64)) * Dd) + t;
    float4 acc = make_float4(0.f, 0.f, 0.f, 0.f);
    #pragma unroll 4
    for (int n = 0; n < 64; ++n) {
        const float w = cf[n];
        float4 v = tp[(size_t)n * (Dd / 4)];
        acc.x = fmaf(w, v.x, acc.x);
        acc.y = fmaf(w, v.y, acc.y);
        acc.z = fmaf(w, v.z, acc.z);
        acc.w = fmaf(w, v.w, acc.w);
    }
    ((float4*)(qpart + ((size_t)seg * Bb + b) * Dd))[t] = acc;
}

// E: logits[b][c] = (q[b] . txt_n[c]) / tau, via txt_t [D,C].
// grid = (B/4, C/256), 256 threads. One thread per c, 4 b's per block.
// No cross-lane reduction: q broadcast from LDS (ds_read_b128), txt_t coalesced.
__global__ void k_logits(const float* __restrict__ qpart, const float* __restrict__ txt_t,
                         const float* __restrict__ log_tau, float* __restrict__ logits) {
    const int b0 = blockIdx.x * 4;
    const int c = blockIdx.y * 256 + threadIdx.x;
    __shared__ float qs[4][Dd];
    for (int i = threadIdx.x; i < 4 * Dd; i += 256) {
        const int j = i >> 9, d = i & (Dd - 1);
        const int b = b0 + j;
        qs[j][d] = qpart[((size_t)0 * Bb + b) * Dd + d] + qpart[((size_t)1 * Bb + b) * Dd + d]
                 + qpart[((size_t)2 * Bb + b) * Dd + d] + qpart[((size_t)3 * Bb + b) * Dd + d];
    }
    __syncthreads();
    float acc0 = 0.f, acc1 = 0.f, acc2 = 0.f, acc3 = 0.f;
    for (int d = 0; d < Dd; d += 4) {
        const float4 q0 = *(const float4*)&qs[0][d];
        const float4 q1 = *(const float4*)&qs[1][d];
        const float4 q2 = *(const float4*)&qs[2][d];
        const float4 q3 = *(const float4*)&qs[3][d];
        const float x0 = txt_t[(size_t)(d + 0) * Cc + c];
        const float x1 = txt_t[(size_t)(d + 1) * Cc + c];
        const float x2 = txt_t[(size_t)(d + 2) * Cc + c];
        const float x3 = txt_t[(size_t)(d + 3) * Cc + c];
        acc0 = fmaf(q0.x, x0, acc0); acc0 = fmaf(q0.y, x1, acc0);
        acc0 = fmaf(q0.z, x2, acc0); acc0 = fmaf(q0.w, x3, acc0);
        acc1 = fmaf(q1.x, x0, acc1); acc1 = fmaf(q1.y, x1, acc1);
        acc1 = fmaf(q1.z, x2, acc1); acc1 = fmaf(q1.w, x3, acc1);
        acc2 = fmaf(q2.x, x0, acc2); acc2 = fmaf(q2.y, x1, acc2);
        acc2 = fmaf(q2.z, x2, acc2); acc2 = fmaf(q2.w, x3, acc2);
        acc3 = fmaf(q3.x, x0, acc3); acc3 = fmaf(q3.y, x1, acc3);
        acc3 = fmaf(q3.z, x2, acc3); acc3 = fmaf(q3.w, x3, acc3);
    }
    float tau = expf(log_tau[0]);
    tau = fminf(fmaxf(tau, 0.01f), 1.0f);
    const float itau = 1.0f / tau;
    logits[(size_t)(b0 + 0) * Cc + c] = acc0 * itau;
    logits[(size_t)(b0 + 1) * Cc + c] = acc1 * itau;
    logits[(size_t)(b0 + 2) * Cc + c] = acc2 * itau;
    logits[(size_t)(b0 + 3) * Cc + c] = acc3 * itau;
}

// E2: per-b LSE + NLL. grid = B blocks, 256 threads (4 c per thread).
__global__ void k_lse(const float* __restrict__ logits, const int* __restrict__ pid,
                      float* __restrict__ nll) {
    const int b = blockIdx.x;
    const int t = threadIdx.x;
    const float4 l4 = ((const float4*)(logits + (size_t)b * Cc))[t];
    float m = fmaxf(fmaxf(l4.x, l4.y), fmaxf(l4.z, l4.w));
    __shared__ float redm[4], reds[4];
    m = waveReduceMax(m);
    if ((t & 63) == 0) redm[t >> 6] = m;
    __syncthreads();
    m = fmaxf(fmaxf(redm[0], redm[1]), fmaxf(redm[2], redm[3]));
    float e = expf(l4.x - m) + expf(l4.y - m) + expf(l4.z - m) + expf(l4.w - m);
    e = waveReduceSum(e);
    if ((t & 63) == 0) reds[t >> 6] = e;
    __syncthreads();
    if (t == 0) {
        const float S = reds[0] + reds[1] + reds[2] + reds[3];
        const float lse = m + logf(S);
        nll[b] = lse - logits[(size_t)b * Cc + pid[b]];
    }
}

// F: mean over B. 1 block, 256 threads.
__global__ void k_mean(const float* __restrict__ nll, float* __restrict__ out) {
    float v = nll[threadIdx.x];
    __shared__ float red[4];
    v = waveReduceSum(v);
    if ((threadIdx.x & 63) == 0) red[threadIdx.x >> 6] = v;
    __syncthreads();
    if (threadIdx.x == 0) out[0] = (red[0] + red[1] + red[2] + red[3]) * (1.0f / (float)Bb);
}

extern "C" void kernel_launch(void* const* d_in, const int* in_sizes, int n_in,
                              void* d_out, int out_size, void* d_ws, size_t ws_size,
                              hipStream_t stream) {
    const float* toks = (const float*)d_in[0];     // [B,N,D] fp32
    const float* txt = (const float*)d_in[1];      // [C,D] fp32
    const float* log_tau = (const float*)d_in[2];
    const float* log_attn_tau = (const float*)d_in[3];
    const int* pid = (const int*)d_in[4];          // [B] int32
    float* out = (float*)d_out;

    float* ws = (float*)d_ws;
    float* txt_n  = ws;                            // C*D
    float* txt_t  = txt_n + (size_t)Cc * Dd;       // D*C
    float* coef   = txt_t + (size_t)Dd * Cc;       // B*N
    float* simsgt = coef + Bb * Nn;                // B*N
    float* invn   = simsgt + Bb * Nn;              // B*N
    float* qpart  = invn + Bb * Nn;                // 4*B*D
    float* logits = qpart + (size_t)4 * Bb * Dd;   // B*C
    float* nll    = logits + (size_t)Bb * Cc;      // B

    k_txtnorm<<<Cc, 64, 0, stream>>>(txt, txt_n);
    k_transpose<<<dim3(Cc / 32, Dd / 32), 256, 0, stream>>>(txt_n, txt_t);
    k_simgt<<<(Bb * Nn) / 4, 256, 0, stream>>>(toks, txt_n, pid, simsgt, invn);
    k_softmax<<<Bb, 256, 0, stream>>>(simsgt, invn, log_attn_tau, coef);
    k_qpart<<<dim3(Bb, 4), 128, 0, stream>>>(toks, coef, qpart);
    k_logits<<<dim3(Bb / 4, Cc / 256), 256, 0, stream>>>(qpart, txt_t, log_tau, logits);
    k_lse<<<Bb, 256, 0, stream>>>(logits, pid, nll);
    k_mean<<<1, 256, 0, stream>>>(nll, out);
}

// Round 3
// 219.046 us; speedup vs baseline: 1.6264x; 1.3124x over previous
//
#include <hip/hip_runtime.h>
#include <math.h>

#define Bb 256
#define Nn 256
#define Dd 512
#define Cc 1024
#define KC 8          // split-K chunks in logits
#define KD (Dd / KC)  // 64 d per chunk

__device__ __forceinline__ float waveReduceSum(float v) {
    #pragma unroll
    for (int off = 32; off > 0; off >>= 1)
        v += __shfl_xor(v, off, 64);
    return v;
}
__device__ __forceinline__ float waveReduceMax(float v) {
    #pragma unroll
    for (int off = 32; off > 0; off >>= 1)
        v = fmaxf(v, __shfl_xor(v, off, 64));
    return v;
}

// A: normalize text rows. grid = Cc blocks, 64 threads (1 wave).
__global__ void k_txtnorm(const float* __restrict__ txt, float* __restrict__ txt_n) {
    const int c = blockIdx.x;
    const int lane = threadIdx.x;
    const float* row = txt + (size_t)c * Dd + lane * 8;
    float4 a = *(const float4*)row;
    float4 b = *(const float4*)(row + 4);
    float ss = a.x*a.x + a.y*a.y + a.z*a.z + a.w*a.w
             + b.x*b.x + b.y*b.y + b.z*b.z + b.w*b.w;
    ss = waveReduceSum(ss);
    const float inv = 1.0f / fmaxf(sqrtf(ss), 1e-12f);
    float* out = txt_n + (size_t)c * Dd + lane * 8;
    a.x *= inv; a.y *= inv; a.z *= inv; a.w *= inv;
    b.x *= inv; b.y *= inv; b.z *= inv; b.w *= inv;
    *(float4*)out = a;
    *(float4*)(out + 4) = b;
}

// A2: transpose txt_n [C,D] -> txt_t [D,C]. grid = (C/32, D/32), 256 threads.
__global__ void k_transpose(const float* __restrict__ txt_n, float* __restrict__ txt_t) {
    __shared__ float tile[32][33];
    const int c0 = blockIdx.x * 32;
    const int d0 = blockIdx.y * 32;
    const int tx = threadIdx.x & 31;
    const int ty = threadIdx.x >> 5;
    #pragma unroll
    for (int r = ty; r < 32; r += 8)
        tile[r][tx] = txt_n[(size_t)(c0 + r) * Dd + d0 + tx];
    __syncthreads();
    #pragma unroll
    for (int r = ty; r < 32; r += 8)
        txt_t[(size_t)(d0 + r) * Cc + c0 + tx] = tile[tx][r];
}

// B (fused simgt+softmax+qpart): ONE pass over tokens with online softmax.
// grid = B blocks, 1024 threads (16 waves, 16 rows each).
// q[b][d] = sum_n softmax_n(sims_gt/at) * invn_n * tok[b][n][d]
__global__ void __launch_bounds__(1024) k_attn_q(const float* __restrict__ toks,
                                                 const float* __restrict__ txt_n,
                                                 const int* __restrict__ pid,
                                                 const float* __restrict__ log_attn_tau,
                                                 float* __restrict__ q) {
    const int b = blockIdx.x;
    const int tid = threadIdx.x;
    const int wv = tid >> 6;     // 0..15
    const int lane = tid & 63;
    __shared__ float xg[Dd];
    __shared__ float qpart_s[16][Dd];   // 32 KB
    __shared__ float ms[16], Ss[16];
    const int g = pid[b];
    if (tid < Dd) xg[tid] = txt_n[(size_t)g * Dd + tid];
    __syncthreads();
    float at = expf(log_attn_tau[0]);
    at = fminf(fmaxf(at, 0.01f), 1.0f);
    const float iat = 1.0f / at;

    const float4 xg0 = *(const float4*)&xg[lane * 8];
    const float4 xg1 = *(const float4*)&xg[lane * 8 + 4];

    float m = -INFINITY, S = 0.0f;
    float qa[8] = {0.f, 0.f, 0.f, 0.f, 0.f, 0.f, 0.f, 0.f};

    const float* base = toks + ((size_t)b * Nn + wv * 16) * Dd + lane * 8;
    float4 t0 = *(const float4*)base;
    float4 t1 = *(const float4*)(base + 4);
    #pragma unroll 4
    for (int r = 0; r < 16; ++r) {
        float4 n0, n1;
        if (r < 15) {   // prefetch next row
            const float* p = base + (size_t)(r + 1) * Dd;
            n0 = *(const float4*)p;
            n1 = *(const float4*)(p + 4);
        }
        float dot = t0.x*xg0.x + t0.y*xg0.y + t0.z*xg0.z + t0.w*xg0.w
                  + t1.x*xg1.x + t1.y*xg1.y + t1.z*xg1.z + t1.w*xg1.w;
        float ss  = t0.x*t0.x + t0.y*t0.y + t0.z*t0.z + t0.w*t0.w
                  + t1.x*t1.x + t1.y*t1.y + t1.z*t1.z + t1.w*t1.w;
        dot = waveReduceSum(dot);
        ss = waveReduceSum(ss);
        const float inv = 1.0f / fmaxf(sqrtf(ss), 1e-12f);
        const float s = dot * inv;     // lane-invariant -> wave-uniform branch
        if (s > m) {
            const float sc = expf((m - s) * iat);   // first iter: exp(-inf)=0
            S = S * sc + 1.0f;
            qa[0] = qa[0]*sc + inv*t0.x; qa[1] = qa[1]*sc + inv*t0.y;
            qa[2] = qa[2]*sc + inv*t0.z; qa[3] = qa[3]*sc + inv*t0.w;
            qa[4] = qa[4]*sc + inv*t1.x; qa[5] = qa[5]*sc + inv*t1.y;
            qa[6] = qa[6]*sc + inv*t1.z; qa[7] = qa[7]*sc + inv*t1.w;
            m = s;
        } else {
            const float e = expf((s - m) * iat);
            S += e;
            const float w = e * inv;
            qa[0] = fmaf(w, t0.x, qa[0]); qa[1] = fmaf(w, t0.y, qa[1]);
            qa[2] = fmaf(w, t0.z, qa[2]); qa[3] = fmaf(w, t0.w, qa[3]);
            qa[4] = fmaf(w, t1.x, qa[4]); qa[5] = fmaf(w, t1.y, qa[5]);
            qa[6] = fmaf(w, t1.z, qa[6]); qa[7] = fmaf(w, t1.w, qa[7]);
        }
        t0 = n0; t1 = n1;
    }
    #pragma unroll
    for (int j = 0; j < 8; ++j) qpart_s[wv][lane * 8 + j] = qa[j];
    if (lane == 0) { ms[wv] = m; Ss[wv] = S; }
    __syncthreads();
    if (tid < Dd) {
        float M = -INFINITY;
        #pragma unroll
        for (int w = 0; w < 16; ++w) M = fmaxf(M, ms[w]);
        float Stot = 0.f, acc = 0.f;
        #pragma unroll
        for (int w = 0; w < 16; ++w) {
            const float sc = expf((ms[w] - M) * iat);
            Stot = fmaf(Ss[w], sc, Stot);
            acc = fmaf(qpart_s[w][tid], sc, acc);
        }
        q[(size_t)b * Dd + tid] = acc / Stot;
    }
}

// E: split-K logits partials. grid = (B/4, KC), 256 threads.
// part[kc][b][c] = sum_{d in chunk} q[b][d] * txt_t[d][c]
__global__ void k_logits(const float* __restrict__ q, const float* __restrict__ txt_t,
                         float* __restrict__ part) {
    const int b0 = blockIdx.x * 4;
    const int kc = blockIdx.y;
    const int d0 = kc * KD;
    const int t = threadIdx.x;     // covers 4 c's each (float4), 1024 c total
    __shared__ float qs[4][KD];
    {
        const int j = t >> 6, d = t & 63;
        qs[j][d] = q[(size_t)(b0 + j) * Dd + d0 + d];
    }
    __syncthreads();
    const float4* xt = (const float4*)txt_t;   // [D][C/4]
    float4 a0 = {0,0,0,0}, a1 = {0,0,0,0}, a2 = {0,0,0,0}, a3 = {0,0,0,0};
    #pragma unroll 4
    for (int d = 0; d < KD; d += 4) {
        const float4 q0 = *(const float4*)&qs[0][d];
        const float4 q1 = *(const float4*)&qs[1][d];
        const float4 q2 = *(const float4*)&qs[2][d];
        const float4 q3 = *(const float4*)&qs[3][d];
        const float4 x0 = xt[(size_t)(d0 + d + 0) * (Cc / 4) + t];
        const float4 x1 = xt[(size_t)(d0 + d + 1) * (Cc / 4) + t];
        const float4 x2 = xt[(size_t)(d0 + d + 2) * (Cc / 4) + t];
        const float4 x3 = xt[(size_t)(d0 + d + 3) * (Cc / 4) + t];
        a0.x = fmaf(q0.x,x0.x,a0.x); a0.y = fmaf(q0.x,x0.y,a0.y); a0.z = fmaf(q0.x,x0.z,a0.z); a0.w = fmaf(q0.x,x0.w,a0.w);
        a0.x = fmaf(q0.y,x1.x,a0.x); a0.y = fmaf(q0.y,x1.y,a0.y); a0.z = fmaf(q0.y,x1.z,a0.z); a0.w = fmaf(q0.y,x1.w,a0.w);
        a0.x = fmaf(q0.z,x2.x,a0.x); a0.y = fmaf(q0.z,x2.y,a0.y); a0.z = fmaf(q0.z,x2.z,a0.z); a0.w = fmaf(q0.z,x2.w,a0.w);
        a0.x = fmaf(q0.w,x3.x,a0.x); a0.y = fmaf(q0.w,x3.y,a0.y); a0.z = fmaf(q0.w,x3.z,a0.z); a0.w = fmaf(q0.w,x3.w,a0.w);
        a1.x = fmaf(q1.x,x0.x,a1.x); a1.y = fmaf(q1.x,x0.y,a1.y); a1.z = fmaf(q1.x,x0.z,a1.z); a1.w = fmaf(q1.x,x0.w,a1.w);
        a1.x = fmaf(q1.y,x1.x,a1.x); a1.y = fmaf(q1.y,x1.y,a1.y); a1.z = fmaf(q1.y,x1.z,a1.z); a1.w = fmaf(q1.y,x1.w,a1.w);
        a1.x = fmaf(q1.z,x2.x,a1.x); a1.y = fmaf(q1.z,x2.y,a1.y); a1.z = fmaf(q1.z,x2.z,a1.z); a1.w = fmaf(q1.z,x2.w,a1.w);
        a1.x = fmaf(q1.w,x3.x,a1.x); a1.y = fmaf(q1.w,x3.y,a1.y); a1.z = fmaf(q1.w,x3.z,a1.z); a1.w = fmaf(q1.w,x3.w,a1.w);
        a2.x = fmaf(q2.x,x0.x,a2.x); a2.y = fmaf(q2.x,x0.y,a2.y); a2.z = fmaf(q2.x,x0.z,a2.z); a2.w = fmaf(q2.x,x0.w,a2.w);
        a2.x = fmaf(q2.y,x1.x,a2.x); a2.y = fmaf(q2.y,x1.y,a2.y); a2.z = fmaf(q2.y,x1.z,a2.z); a2.w = fmaf(q2.y,x1.w,a2.w);
        a2.x = fmaf(q2.z,x2.x,a2.x); a2.y = fmaf(q2.z,x2.y,a2.y); a2.z = fmaf(q2.z,x2.z,a2.z); a2.w = fmaf(q2.z,x2.w,a2.w);
        a2.x = fmaf(q2.w,x3.x,a2.x); a2.y = fmaf(q2.w,x3.y,a2.y); a2.z = fmaf(q2.w,x3.z,a2.z); a2.w = fmaf(q2.w,x3.w,a2.w);
        a3.x = fmaf(q3.x,x0.x,a3.x); a3.y = fmaf(q3.x,x0.y,a3.y); a3.z = fmaf(q3.x,x0.z,a3.z); a3.w = fmaf(q3.x,x0.w,a3.w);
        a3.x = fmaf(q3.y,x1.x,a3.x); a3.y = fmaf(q3.y,x1.y,a3.y); a3.z = fmaf(q3.y,x1.z,a3.z); a3.w = fmaf(q3.y,x1.w,a3.w);
        a3.x = fmaf(q3.z,x2.x,a3.x); a3.y = fmaf(q3.z,x2.y,a3.y); a3.z = fmaf(q3.z,x2.z,a3.z); a3.w = fmaf(q3.z,x2.w,a3.w);
        a3.x = fmaf(q3.w,x3.x,a3.x); a3.y = fmaf(q3.w,x3.y,a3.y); a3.z = fmaf(q3.w,x3.z,a3.z); a3.w = fmaf(q3.w,x3.w,a3.w);
    }
    float* pb = part + ((size_t)kc * Bb + b0) * Cc;
    ((float4*)(pb + 0 * Cc))[t] = a0;
    ((float4*)(pb + 1 * Cc))[t] = a1;
    ((float4*)(pb + 2 * Cc))[t] = a2;
    ((float4*)(pb + 3 * Cc))[t] = a3;
}

// E2: sum K-partials, scale by 1/tau, LSE + NLL. grid = B blocks, 256 threads.
__global__ void k_lse(const float* __restrict__ part, const int* __restrict__ pid,
                      const float* __restrict__ log_tau, float* __restrict__ nll) {
    const int b = blockIdx.x;
    const int t = threadIdx.x;   // 4 c's each
    float4 l = {0,0,0,0};
    #pragma unroll
    for (int kc = 0; kc < KC; ++kc) {
        const float4 p = ((const float4*)(part + ((size_t)kc * Bb + b) * Cc))[t];
        l.x += p.x; l.y += p.y; l.z += p.z; l.w += p.w;
    }
    float tau = expf(log_tau[0]);
    tau = fminf(fmaxf(tau, 0.01f), 1.0f);
    const float itau = 1.0f / tau;
    l.x *= itau; l.y *= itau; l.z *= itau; l.w *= itau;

    const int g = pid[b];
    __shared__ float redm[4], reds[4], sgt;
    if ((g >> 2) == t) {
        const float v[4] = {l.x, l.y, l.z, l.w};
        sgt = v[g & 3];
    }
    float m = fmaxf(fmaxf(l.x, l.y), fmaxf(l.z, l.w));
    m = waveReduceMax(m);
    if ((t & 63) == 0) redm[t >> 6] = m;
    __syncthreads();
    m = fmaxf(fmaxf(redm[0], redm[1]), fmaxf(redm[2], redm[3]));
    float e = expf(l.x - m) + expf(l.y - m) + expf(l.z - m) + expf(l.w - m);
    e = waveReduceSum(e);
    if ((t & 63) == 0) reds[t >> 6] = e;
    __syncthreads();
    if (t == 0) {
        const float S = reds[0] + reds[1] + reds[2] + reds[3];
        nll[b] = m + logf(S) - sgt;
    }
}

// F: mean over B. 1 block, 256 threads.
__global__ void k_mean(const float* __restrict__ nll, float* __restrict__ out) {
    float v = nll[threadIdx.x];
    __shared__ float red[4];
    v = waveReduceSum(v);
    if ((threadIdx.x & 63) == 0) red[threadIdx.x >> 6] = v;
    __syncthreads();
    if (threadIdx.x == 0) out[0] = (red[0] + red[1] + red[2] + red[3]) * (1.0f / (float)Bb);
}

extern "C" void kernel_launch(void* const* d_in, const int* in_sizes, int n_in,
                              void* d_out, int out_size, void* d_ws, size_t ws_size,
                              hipStream_t stream) {
    const float* toks = (const float*)d_in[0];     // [B,N,D] fp32
    const float* txt = (const float*)d_in[1];      // [C,D] fp32
    const float* log_tau = (const float*)d_in[2];
    const float* log_attn_tau = (const float*)d_in[3];
    const int* pid = (const int*)d_in[4];          // [B] int32
    float* out = (float*)d_out;

    float* ws = (float*)d_ws;
    float* txt_n = ws;                             // C*D
    float* txt_t = txt_n + (size_t)Cc * Dd;        // D*C
    float* q     = txt_t + (size_t)Dd * Cc;        // B*D
    float* part  = q + (size_t)Bb * Dd;            // KC*B*C
    float* nll   = part + (size_t)KC * Bb * Cc;    // B

    k_txtnorm<<<Cc, 64, 0, stream>>>(txt, txt_n);
    k_transpose<<<dim3(Cc / 32, Dd / 32), 256, 0, stream>>>(txt_n, txt_t);
    k_attn_q<<<Bb, 1024, 0, stream>>>(toks, txt_n, pid, log_attn_tau, q);
    k_logits<<<dim3(Bb / 4, KC), 256, 0, stream>>>(q, txt_t, part);
    k_lse<<<Bb, 256, 0, stream>>>(part, pid, log_tau, nll);
    k_mean<<<1, 256, 0, stream>>>(nll, out);
}